// Round 9
// baseline (529.583 us; speedup 1.0000x reference)
//
#include <hip/hip_runtime.h>
#include <math.h>

#define GRIDN    128
#define NRAYS    16384
#define STEPSZ   0.5f
#define MAXSTEPS 320
#define SEGS     32
#define SPS      (MAXSTEPS / SEGS)   // 10 steps per segment
#define RPB      8                   // rays per block
#define TPB      (RPB * SEGS)        // 256 threads; wave = 8 rays x 8 segs
#define NVOX     (GRIDN * GRIDN * GRIDN)
// 32-B record per VOXEL: [0:2) f16 density, [2:4) f16 scale, [4:31) 27x int8
// SH quant (sh ~= scale*q), [31] pad. Voxel-indexed; empty voxels = zeros.
#define PACK_BYTES ((size_t)NVOX * 32)

// ---------------------------------------------------------------------------
// Prologue: int8-quantizing repack (round-8 proven). Wave handles 64 voxels:
// float4 coalesced span-read of the 64 sh rows into LDS (stride-27 row reads
// conflict-free), per-lane rowmax/quantize, 32-B record stores.
// 5 blocks/CU (LDS-capped: 27.6 KB x 5 = 138 KB of 160).
// ---------------------------------------------------------------------------
__global__ __launch_bounds__(256, 5)
void repack_kernel(const int*   __restrict__ links,
                   const float* __restrict__ density,
                   const float* __restrict__ sh,
                   unsigned int* __restrict__ pack)
{
    __shared__ float buf[4][64 * 27];   // 27648 B/block
    const int lane  = threadIdx.x & 63;
    const int wv    = threadIdx.x >> 6;
    const int vbase = (blockIdx.x * 4 + wv) * 64;

    // span read: 64 rows = 1728 floats = 432 float4 (16B-aligned: vbase*108)
    float* b = buf[wv];
    const float4* src4 = (const float4*)(sh + (size_t)vbase * 27);
    #pragma unroll
    for (int it = 0; it < 7; it++) {
        const int idx = it * 64 + lane;
        if (idx < 432) {
            const float4 v = src4[idx];
            b[idx * 4 + 0] = v.x; b[idx * 4 + 1] = v.y;
            b[idx * 4 + 2] = v.z; b[idx * 4 + 3] = v.w;
        }
    }

    const int v   = vbase + lane;
    const int lnk = links[v];
    const float dens = (lnk >= 0) ? density[lnk] : 0.0f;
    __syncthreads();

    // gather this voxel's row (every path writes all 27 -> stays in regs)
    float row[27];
    if (lnk >= 0) {
        if (lnk >= vbase && lnk < vbase + 64) {
            const float* r = b + (lnk - vbase) * 27;   // stride-27: conflict-free
            #pragma unroll
            for (int k = 0; k < 27; k++) row[k] = r[k];
        } else {
            const float* r = sh + (size_t)lnk * 27;    // rare general-links gather
            #pragma unroll
            for (int k = 0; k < 27; k++) row[k] = r[k];
        }
    } else {
        #pragma unroll
        for (int k = 0; k < 27; k++) row[k] = 0.0f;
    }

    // quantize: scale = rowmax/127, q = rint(sh/scale) in [-127,127]
    float mx = 0.0f;
    #pragma unroll
    for (int k = 0; k < 27; k++) mx = fmaxf(mx, fabsf(row[k]));
    const float scale = mx * (1.0f / 127.0f);
    const float inv   = (mx > 0.0f) ? (127.0f / mx) : 0.0f;

    unsigned int d[8];
    union { _Float16 h; unsigned short u; } cvt;
    cvt.h = (_Float16)dens;
    const unsigned int dh = cvt.u;
    cvt.h = (_Float16)scale;
    d[0] = dh | ((unsigned int)cvt.u << 16);
    #pragma unroll
    for (int j = 0; j < 7; j++) {
        unsigned int w = 0;
        #pragma unroll
        for (int e = 0; e < 4; e++) {
            const int k = j * 4 + e;
            int q = 0;
            if (k < 27) {
                q = (int)rintf(row[k] * inv);
                q = q > 127 ? 127 : (q < -127 ? -127 : q);
            }
            w |= ((unsigned int)(unsigned char)(signed char)q) << (e * 8);
        }
        d[1 + j] = w;
    }

    uint4* dst = (uint4*)(pack + (size_t)v * 8);
    dst[0] = make_uint4(d[0], d[1], d[2], d[3]);
    dst[1] = make_uint4(d[4], d[5], d[6], d[7]);
}

// ---------------------------------------------------------------------------
// March: round-8 proven structure; this round only lifts the self-imposed
// occupancy cap (6 -> 8 blocks/CU: VGPR 40 and 8 KB LDS both fit 32 waves/CU;
// at VALUBusy ~49% the extra TLP has work to overlap with gather latency)
// and pads the stitch array stride 8 -> 9 floats (kills the 8-way LDS bank
// conflict on partial writes, SQ_LDS_BANK_CONFLICT 131072 -> ~0).
// ---------------------------------------------------------------------------
#define QB(w, b) ((float)(int)(signed char)(((w) >> ((b) * 8)) & 0xffu))

template <bool PACKED>
__global__ __launch_bounds__(TPB, 8)
void march_kernel(const float* __restrict__ origins,
                  const float* __restrict__ dirs,
                  const int*   __restrict__ links,
                  const float* __restrict__ density,
                  const float* __restrict__ sh,
                  const unsigned int* __restrict__ pack,
                  float* __restrict__ out)
{
    __shared__ float part[SEGS][RPB][9];   // stride 9: conflict-free

    const int tid = threadIdx.x;
    const int r   = tid & (RPB - 1);
    const int seg = tid / RPB;
    const int ray = blockIdx.x * RPB + r;

    // ---- ray setup ----
    const float owx = origins[ray * 3 + 0];
    const float owy = origins[ray * 3 + 1];
    const float owz = origins[ray * 3 + 2];
    const float dwx = dirs[ray * 3 + 0];
    const float dwy = dirs[ray * 3 + 1];
    const float dwz = dirs[ray * 3 + 2];

    const float invn = 1.0f / sqrtf(dwx * dwx + dwy * dwy + dwz * dwz);
    const float vx = dwx * invn, vy = dwy * invn, vz = dwz * invn;

    const float ox = 63.5f + owx * 64.0f;
    const float oy = 63.5f + owy * 64.0f;
    const float oz = 63.5f + owz * 64.0f;

    const float sxx = vx * 64.0f, syy = vy * 64.0f, szz = vz * 64.0f;
    const float ds  = 1.0f / sqrtf(sxx * sxx + syy * syy + szz * szz);
    const float dx = sxx * ds, dy = syy * ds, dz = szz * ds;

    float shm[9];
    shm[0] = 0.28209479177387814f;
    shm[1] = -0.4886025119029199f * vy;
    shm[2] =  0.4886025119029199f * vz;
    shm[3] = -0.4886025119029199f * vx;
    shm[4] =  1.0925484305920792f * vx * vy;
    shm[5] = -1.0925484305920792f * vy * vz;
    shm[6] =  0.31539156525252005f * (2.0f * vz * vz - vx * vx - vy * vy);
    shm[7] = -1.0925484305920792f * vx * vz;
    shm[8] =  0.5462742152960396f * (vx * vx - vy * vy);

    float t0 = 0.0f, tmax = 1e9f;
    {
        const float o3[3] = { ox, oy, oz };
        const float d3[3] = { dx, dy, dz };
        #pragma unroll
        for (int a = 0; a < 3; a++) {
            if (d3[a] != 0.0f) {
                float inv = 1.0f / d3[a];
                float ta = (-0.5f  - o3[a]) * inv;
                float tb = (127.5f - o3[a]) * inv;
                t0   = fmaxf(t0,   fminf(ta, tb));
                tmax = fminf(tmax, fmaxf(ta, tb));
            }
        }
    }

    float ll = 0.0f;
    float light = 1.0f;
    float aR = 0, aG = 0, aB = 0, aA = 0, aD1 = 0, aD2 = 0;

    int cached_cell = -1;
    float csig[8], cr0[8], cr1[8], cr2[8];

    const int k0 = seg * SPS;
    for (int i = 0; i < SPS; i++) {
        const float t = t0 + (float)(k0 + i) * STEPSZ;
        if (t > tmax) break;

        float px = fminf(fmaxf(ox + t * dx, 0.0f), 127.0f);
        float py = fminf(fmaxf(oy + t * dy, 0.0f), 127.0f);
        float pz = fminf(fmaxf(oz + t * dz, 0.0f), 127.0f);
        const int lx = min(max((int)px, 0), 126);
        const int ly = min(max((int)py, 0), 126);
        const int lz = min(max((int)pz, 0), 126);
        const float fx = px - (float)lx;
        const float fy = py - (float)ly;
        const float fz = pz - (float)lz;

        const int cell = (lx << 14) | (ly << 7) | lz;
        if (cell != cached_cell) {
            cached_cell = cell;
            if (PACKED) {
                #pragma unroll
                for (int c = 0; c < 8; c++) {
                    const int off = (((c >> 2) & 1) << 14) + (((c >> 1) & 1) << 7) + (c & 1);
                    const uint4* pr = (const uint4*)(pack + (size_t)(cell + off) * 8);
                    const uint4 A = pr[0], Bq = pr[1];
                    const unsigned int d1 = A.y,  d2 = A.z,  d3 = A.w;
                    const unsigned int d4 = Bq.x, d5 = Bq.y, d6 = Bq.z, d7 = Bq.w;

                    union { unsigned short u; _Float16 h; } cv;
                    cv.u = (unsigned short)(A.x & 0xffffu);
                    csig[c] = (float)cv.h;
                    cv.u = (unsigned short)(A.x >> 16);
                    const float s = (float)cv.h;

                    const float s0 = shm[0]*QB(d1,0) + shm[1]*QB(d1,1) + shm[2]*QB(d1,2)
                                   + shm[3]*QB(d1,3) + shm[4]*QB(d2,0) + shm[5]*QB(d2,1)
                                   + shm[6]*QB(d2,2) + shm[7]*QB(d2,3) + shm[8]*QB(d3,0);
                    const float s1 = shm[0]*QB(d3,1) + shm[1]*QB(d3,2) + shm[2]*QB(d3,3)
                                   + shm[3]*QB(d4,0) + shm[4]*QB(d4,1) + shm[5]*QB(d4,2)
                                   + shm[6]*QB(d4,3) + shm[7]*QB(d5,0) + shm[8]*QB(d5,1);
                    const float s2 = shm[0]*QB(d5,2) + shm[1]*QB(d5,3) + shm[2]*QB(d6,0)
                                   + shm[3]*QB(d6,1) + shm[4]*QB(d6,2) + shm[5]*QB(d6,3)
                                   + shm[6]*QB(d7,0) + shm[7]*QB(d7,1) + shm[8]*QB(d7,2);
                    cr0[c] = s * s0;
                    cr1[c] = s * s1;
                    cr2[c] = s * s2;
                }
            } else {
                #pragma unroll
                for (int c = 0; c < 8; c++) {
                    const int cdx = (c >> 2) & 1, cdy = (c >> 1) & 1, cdz = c & 1;
                    const int idx = cell + (cdx << 14) + (cdy << 7) + cdz;
                    const int lnk = links[idx];
                    float sg = 0, q0 = 0, q1 = 0, q2 = 0;
                    if (lnk >= 0) {
                        sg = density[lnk];
                        const float* row = sh + (size_t)lnk * 27;
                        #pragma unroll
                        for (int k = 0; k < 9; k++) {
                            const float m = shm[k];
                            q0 += m * row[k];
                            q1 += m * row[9 + k];
                            q2 += m * row[18 + k];
                        }
                    }
                    csig[c] = sg; cr0[c] = q0; cr1[c] = q1; cr2[c] = q2;
                }
            }
        }

        const float gx1 = fx, gx0 = 1.0f - fx;
        const float gy1 = fy, gy0 = 1.0f - fy;
        const float gz1 = fz, gz0 = 1.0f - fz;
        float w[8];
        w[0] = gx0*gy0*gz0; w[1] = gx0*gy0*gz1; w[2] = gx0*gy1*gz0; w[3] = gx0*gy1*gz1;
        w[4] = gx1*gy0*gz0; w[5] = gx1*gy0*gz1; w[6] = gx1*gy1*gz0; w[7] = gx1*gy1*gz1;

        float sigma = 0, c0 = 0, c1 = 0, c2 = 0;
        #pragma unroll
        for (int c = 0; c < 8; c++) {
            sigma += w[c] * csig[c];
            c0    += w[c] * cr0[c];
            c1    += w[c] * cr1[c];
            c2    += w[c] * cr2[c];
        }

        const float la = -STEPSZ * fmaxf(sigma, 0.0f) * ds;
        const float e  = __expf(la);
        const float ws = light * (1.0f - e);
        c0 = fmaxf(c0 + 0.5f, 0.0f);
        c1 = fmaxf(c1 + 0.5f, 0.0f);
        c2 = fmaxf(c2 + 0.5f, 0.0f);

        aR += ws * c0; aG += ws * c1; aB += ws * c2;
        aA += ws;
        const float dd = t * ds;
        aD1 += ws * dd;
        aD2 += ws * dd * dd;
        light *= e;
        ll    += la;
    }

    part[seg][r][0] = aR;  part[seg][r][1] = aG;  part[seg][r][2] = aB;
    part[seg][r][3] = aA;  part[seg][r][4] = aD1; part[seg][r][5] = aD2;
    part[seg][r][6] = ll;
    __syncthreads();

    if (tid < RPB) {
        float pre = 0.0f;
        float R = 0, G = 0, Bc = 0, A = 0, D1 = 0, D2 = 0;
        for (int s = 0; s < SEGS; s++) {
            const float T = __expf(pre);
            R  += T * part[s][tid][0];
            G  += T * part[s][tid][1];
            Bc += T * part[s][tid][2];
            A  += T * part[s][tid][3];
            D1 += T * part[s][tid][4];
            D2 += T * part[s][tid][5];
            pre += part[s][tid][6];
        }
        const float bg    = __expf(pre);
        const float denom = fmaxf(A, 1e-10f);
        const float E     = D1 / denom;
        const float ov    = D2 - 2.0f * E * D1 + E * E * A;

        const int o = (blockIdx.x * RPB + tid) * 6;
        out[o + 0] = R  + bg;
        out[o + 1] = G  + bg;
        out[o + 2] = Bc + bg;
        out[o + 3] = A;
        out[o + 4] = E;
        out[o + 5] = ov / denom;
    }
}

extern "C" void kernel_launch(void* const* d_in, const int* in_sizes, int n_in,
                              void* d_out, int out_size, void* d_ws, size_t ws_size,
                              hipStream_t stream) {
    const float* origins = (const float*)d_in[0];
    const float* dirs    = (const float*)d_in[1];
    const int*   links   = (const int*)d_in[2];
    const float* density = (const float*)d_in[3];
    const float* sh      = (const float*)d_in[4];
    float* out = (float*)d_out;

    dim3 mgrid(NRAYS / RPB);   // 2048 blocks
    dim3 mblock(TPB);          // 256 threads = 8 rays x 32 segments

    if (ws_size >= PACK_BYTES) {
        unsigned int* pack = (unsigned int*)d_ws;
        repack_kernel<<<dim3(NVOX / 256), dim3(256), 0, stream>>>(links, density, sh, pack);
        march_kernel<true><<<mgrid, mblock, 0, stream>>>(
            origins, dirs, links, density, sh, pack, out);
    } else {
        march_kernel<false><<<mgrid, mblock, 0, stream>>>(
            origins, dirs, links, density, sh, (const unsigned int*)nullptr, out);
    }
}

// Round 10
// 442.452 us; speedup vs baseline: 1.1969x; 1.1969x over previous
//
#include <hip/hip_runtime.h>
#include <math.h>

#define GRIDN    128
#define NRAYS    16384
#define STEPSZ   0.5f
#define MAXSTEPS 320
#define SEGS     32
#define SPS      (MAXSTEPS / SEGS)   // 10 steps per segment
#define RPB      8                   // rays per block
#define TPB      (RPB * SEGS)        // 256 threads; wave = 8 rays x 8 segs
#define NVOX     (GRIDN * GRIDN * GRIDN)
// 32-B record per VOXEL: [0:2) f16 density, [2:4) f16 scale, [4:31) 27x int8
// SH quant (sh ~= scale*q), [31] pad. Voxel-indexed; empty voxels = zeros.
#define PACK_BYTES ((size_t)NVOX * 32)

// ---------------------------------------------------------------------------
// Prologue: int8-quantizing repack (round-8 proven, exact config).
// ---------------------------------------------------------------------------
__global__ __launch_bounds__(256, 4)
void repack_kernel(const int*   __restrict__ links,
                   const float* __restrict__ density,
                   const float* __restrict__ sh,
                   unsigned int* __restrict__ pack)
{
    __shared__ float buf[4][64 * 27];   // 27648 B/block
    const int lane  = threadIdx.x & 63;
    const int wv    = threadIdx.x >> 6;
    const int vbase = (blockIdx.x * 4 + wv) * 64;

    // span read: 64 rows = 1728 floats = 432 float4 (16B-aligned: vbase*108)
    float* b = buf[wv];
    const float4* src4 = (const float4*)(sh + (size_t)vbase * 27);
    #pragma unroll
    for (int it = 0; it < 7; it++) {
        const int idx = it * 64 + lane;
        if (idx < 432) {
            const float4 v = src4[idx];
            b[idx * 4 + 0] = v.x; b[idx * 4 + 1] = v.y;
            b[idx * 4 + 2] = v.z; b[idx * 4 + 3] = v.w;
        }
    }

    const int v   = vbase + lane;
    const int lnk = links[v];
    const float dens = (lnk >= 0) ? density[lnk] : 0.0f;
    __syncthreads();

    // gather this voxel's row (every path writes all 27 -> stays in regs)
    float row[27];
    if (lnk >= 0) {
        if (lnk >= vbase && lnk < vbase + 64) {
            const float* r = b + (lnk - vbase) * 27;   // stride-27: conflict-free
            #pragma unroll
            for (int k = 0; k < 27; k++) row[k] = r[k];
        } else {
            const float* r = sh + (size_t)lnk * 27;    // rare general-links gather
            #pragma unroll
            for (int k = 0; k < 27; k++) row[k] = r[k];
        }
    } else {
        #pragma unroll
        for (int k = 0; k < 27; k++) row[k] = 0.0f;
    }

    // quantize: scale = rowmax/127, q = rint(sh/scale) in [-127,127]
    float mx = 0.0f;
    #pragma unroll
    for (int k = 0; k < 27; k++) mx = fmaxf(mx, fabsf(row[k]));
    const float scale = mx * (1.0f / 127.0f);
    const float inv   = (mx > 0.0f) ? (127.0f / mx) : 0.0f;

    unsigned int d[8];
    union { _Float16 h; unsigned short u; } cvt;
    cvt.h = (_Float16)dens;
    const unsigned int dh = cvt.u;
    cvt.h = (_Float16)scale;
    d[0] = dh | ((unsigned int)cvt.u << 16);
    #pragma unroll
    for (int j = 0; j < 7; j++) {
        unsigned int w = 0;
        #pragma unroll
        for (int e = 0; e < 4; e++) {
            const int k = j * 4 + e;
            int q = 0;
            if (k < 27) {
                q = (int)rintf(row[k] * inv);
                q = q > 127 ? 127 : (q < -127 ? -127 : q);
            }
            w |= ((unsigned int)(unsigned char)(signed char)q) << (e * 8);
        }
        d[1 + j] = w;
    }

    uint4* dst = (uint4*)(pack + (size_t)v * 8);
    dst[0] = make_uint4(d[0], d[1], d[2], d[3]);
    dst[1] = make_uint4(d[4], d[5], d[6], d[7]);
}

// ---------------------------------------------------------------------------
// March: round-8 proven config restored EXACTLY (launch_bounds(TPB,6):
// 6 blocks/CU keeps the per-CU ray-tube working set inside the 32 KiB L1 —
// round 9 proved 8 blocks/CU thrashes L1: FETCH 127->377 MB, time +55%).
// Only retained change from round 9: part[] stride 9 (LDS-conflict-free,
// no occupancy impact: 9216 B x 6 = 54 KB/CU).
// ---------------------------------------------------------------------------
#define QB(w, b) ((float)(int)(signed char)(((w) >> ((b) * 8)) & 0xffu))

template <bool PACKED>
__global__ __launch_bounds__(TPB, 6)
void march_kernel(const float* __restrict__ origins,
                  const float* __restrict__ dirs,
                  const int*   __restrict__ links,
                  const float* __restrict__ density,
                  const float* __restrict__ sh,
                  const unsigned int* __restrict__ pack,
                  float* __restrict__ out)
{
    __shared__ float part[SEGS][RPB][9];   // stride 9: conflict-free

    const int tid = threadIdx.x;
    const int r   = tid & (RPB - 1);
    const int seg = tid / RPB;
    const int ray = blockIdx.x * RPB + r;

    // ---- ray setup ----
    const float owx = origins[ray * 3 + 0];
    const float owy = origins[ray * 3 + 1];
    const float owz = origins[ray * 3 + 2];
    const float dwx = dirs[ray * 3 + 0];
    const float dwy = dirs[ray * 3 + 1];
    const float dwz = dirs[ray * 3 + 2];

    const float invn = 1.0f / sqrtf(dwx * dwx + dwy * dwy + dwz * dwz);
    const float vx = dwx * invn, vy = dwy * invn, vz = dwz * invn;

    const float ox = 63.5f + owx * 64.0f;
    const float oy = 63.5f + owy * 64.0f;
    const float oz = 63.5f + owz * 64.0f;

    const float sxx = vx * 64.0f, syy = vy * 64.0f, szz = vz * 64.0f;
    const float ds  = 1.0f / sqrtf(sxx * sxx + syy * syy + szz * szz);
    const float dx = sxx * ds, dy = syy * ds, dz = szz * ds;

    float shm[9];
    shm[0] = 0.28209479177387814f;
    shm[1] = -0.4886025119029199f * vy;
    shm[2] =  0.4886025119029199f * vz;
    shm[3] = -0.4886025119029199f * vx;
    shm[4] =  1.0925484305920792f * vx * vy;
    shm[5] = -1.0925484305920792f * vy * vz;
    shm[6] =  0.31539156525252005f * (2.0f * vz * vz - vx * vx - vy * vy);
    shm[7] = -1.0925484305920792f * vx * vz;
    shm[8] =  0.5462742152960396f * (vx * vx - vy * vy);

    float t0 = 0.0f, tmax = 1e9f;
    {
        const float o3[3] = { ox, oy, oz };
        const float d3[3] = { dx, dy, dz };
        #pragma unroll
        for (int a = 0; a < 3; a++) {
            if (d3[a] != 0.0f) {
                float inv = 1.0f / d3[a];
                float ta = (-0.5f  - o3[a]) * inv;
                float tb = (127.5f - o3[a]) * inv;
                t0   = fmaxf(t0,   fminf(ta, tb));
                tmax = fminf(tmax, fmaxf(ta, tb));
            }
        }
    }

    float ll = 0.0f;
    float light = 1.0f;
    float aR = 0, aG = 0, aB = 0, aA = 0, aD1 = 0, aD2 = 0;

    int cached_cell = -1;
    float csig[8], cr0[8], cr1[8], cr2[8];

    const int k0 = seg * SPS;
    for (int i = 0; i < SPS; i++) {
        const float t = t0 + (float)(k0 + i) * STEPSZ;
        if (t > tmax) break;

        float px = fminf(fmaxf(ox + t * dx, 0.0f), 127.0f);
        float py = fminf(fmaxf(oy + t * dy, 0.0f), 127.0f);
        float pz = fminf(fmaxf(oz + t * dz, 0.0f), 127.0f);
        const int lx = min(max((int)px, 0), 126);
        const int ly = min(max((int)py, 0), 126);
        const int lz = min(max((int)pz, 0), 126);
        const float fx = px - (float)lx;
        const float fy = py - (float)ly;
        const float fz = pz - (float)lz;

        const int cell = (lx << 14) | (ly << 7) | lz;
        if (cell != cached_cell) {
            cached_cell = cell;
            if (PACKED) {
                #pragma unroll
                for (int c = 0; c < 8; c++) {
                    const int off = (((c >> 2) & 1) << 14) + (((c >> 1) & 1) << 7) + (c & 1);
                    const uint4* pr = (const uint4*)(pack + (size_t)(cell + off) * 8);
                    const uint4 A = pr[0], Bq = pr[1];
                    const unsigned int d1 = A.y,  d2 = A.z,  d3 = A.w;
                    const unsigned int d4 = Bq.x, d5 = Bq.y, d6 = Bq.z, d7 = Bq.w;

                    union { unsigned short u; _Float16 h; } cv;
                    cv.u = (unsigned short)(A.x & 0xffffu);
                    csig[c] = (float)cv.h;
                    cv.u = (unsigned short)(A.x >> 16);
                    const float s = (float)cv.h;

                    const float s0 = shm[0]*QB(d1,0) + shm[1]*QB(d1,1) + shm[2]*QB(d1,2)
                                   + shm[3]*QB(d1,3) + shm[4]*QB(d2,0) + shm[5]*QB(d2,1)
                                   + shm[6]*QB(d2,2) + shm[7]*QB(d2,3) + shm[8]*QB(d3,0);
                    const float s1 = shm[0]*QB(d3,1) + shm[1]*QB(d3,2) + shm[2]*QB(d3,3)
                                   + shm[3]*QB(d4,0) + shm[4]*QB(d4,1) + shm[5]*QB(d4,2)
                                   + shm[6]*QB(d4,3) + shm[7]*QB(d5,0) + shm[8]*QB(d5,1);
                    const float s2 = shm[0]*QB(d5,2) + shm[1]*QB(d5,3) + shm[2]*QB(d6,0)
                                   + shm[3]*QB(d6,1) + shm[4]*QB(d6,2) + shm[5]*QB(d6,3)
                                   + shm[6]*QB(d7,0) + shm[7]*QB(d7,1) + shm[8]*QB(d7,2);
                    cr0[c] = s * s0;
                    cr1[c] = s * s1;
                    cr2[c] = s * s2;
                }
            } else {
                #pragma unroll
                for (int c = 0; c < 8; c++) {
                    const int cdx = (c >> 2) & 1, cdy = (c >> 1) & 1, cdz = c & 1;
                    const int idx = cell + (cdx << 14) + (cdy << 7) + cdz;
                    const int lnk = links[idx];
                    float sg = 0, q0 = 0, q1 = 0, q2 = 0;
                    if (lnk >= 0) {
                        sg = density[lnk];
                        const float* row = sh + (size_t)lnk * 27;
                        #pragma unroll
                        for (int k = 0; k < 9; k++) {
                            const float m = shm[k];
                            q0 += m * row[k];
                            q1 += m * row[9 + k];
                            q2 += m * row[18 + k];
                        }
                    }
                    csig[c] = sg; cr0[c] = q0; cr1[c] = q1; cr2[c] = q2;
                }
            }
        }

        const float gx1 = fx, gx0 = 1.0f - fx;
        const float gy1 = fy, gy0 = 1.0f - fy;
        const float gz1 = fz, gz0 = 1.0f - fz;
        float w[8];
        w[0] = gx0*gy0*gz0; w[1] = gx0*gy0*gz1; w[2] = gx0*gy1*gz0; w[3] = gx0*gy1*gz1;
        w[4] = gx1*gy0*gz0; w[5] = gx1*gy0*gz1; w[6] = gx1*gy1*gz0; w[7] = gx1*gy1*gz1;

        float sigma = 0, c0 = 0, c1 = 0, c2 = 0;
        #pragma unroll
        for (int c = 0; c < 8; c++) {
            sigma += w[c] * csig[c];
            c0    += w[c] * cr0[c];
            c1    += w[c] * cr1[c];
            c2    += w[c] * cr2[c];
        }

        const float la = -STEPSZ * fmaxf(sigma, 0.0f) * ds;
        const float e  = __expf(la);
        const float ws = light * (1.0f - e);
        c0 = fmaxf(c0 + 0.5f, 0.0f);
        c1 = fmaxf(c1 + 0.5f, 0.0f);
        c2 = fmaxf(c2 + 0.5f, 0.0f);

        aR += ws * c0; aG += ws * c1; aB += ws * c2;
        aA += ws;
        const float dd = t * ds;
        aD1 += ws * dd;
        aD2 += ws * dd * dd;
        light *= e;
        ll    += la;
    }

    part[seg][r][0] = aR;  part[seg][r][1] = aG;  part[seg][r][2] = aB;
    part[seg][r][3] = aA;  part[seg][r][4] = aD1; part[seg][r][5] = aD2;
    part[seg][r][6] = ll;
    __syncthreads();

    if (tid < RPB) {
        float pre = 0.0f;
        float R = 0, G = 0, Bc = 0, A = 0, D1 = 0, D2 = 0;
        for (int s = 0; s < SEGS; s++) {
            const float T = __expf(pre);
            R  += T * part[s][tid][0];
            G  += T * part[s][tid][1];
            Bc += T * part[s][tid][2];
            A  += T * part[s][tid][3];
            D1 += T * part[s][tid][4];
            D2 += T * part[s][tid][5];
            pre += part[s][tid][6];
        }
        const float bg    = __expf(pre);
        const float denom = fmaxf(A, 1e-10f);
        const float E     = D1 / denom;
        const float ov    = D2 - 2.0f * E * D1 + E * E * A;

        const int o = (blockIdx.x * RPB + tid) * 6;
        out[o + 0] = R  + bg;
        out[o + 1] = G  + bg;
        out[o + 2] = Bc + bg;
        out[o + 3] = A;
        out[o + 4] = E;
        out[o + 5] = ov / denom;
    }
}

extern "C" void kernel_launch(void* const* d_in, const int* in_sizes, int n_in,
                              void* d_out, int out_size, void* d_ws, size_t ws_size,
                              hipStream_t stream) {
    const float* origins = (const float*)d_in[0];
    const float* dirs    = (const float*)d_in[1];
    const int*   links   = (const int*)d_in[2];
    const float* density = (const float*)d_in[3];
    const float* sh      = (const float*)d_in[4];
    float* out = (float*)d_out;

    dim3 mgrid(NRAYS / RPB);   // 2048 blocks
    dim3 mblock(TPB);          // 256 threads = 8 rays x 32 segments

    if (ws_size >= PACK_BYTES) {
        unsigned int* pack = (unsigned int*)d_ws;
        repack_kernel<<<dim3(NVOX / 256), dim3(256), 0, stream>>>(links, density, sh, pack);
        march_kernel<true><<<mgrid, mblock, 0, stream>>>(
            origins, dirs, links, density, sh, pack, out);
    } else {
        march_kernel<false><<<mgrid, mblock, 0, stream>>>(
            origins, dirs, links, density, sh, (const unsigned int*)nullptr, out);
    }
}